// Round 6
// baseline (351.445 us; speedup 1.0000x reference)
//
#include <hip/hip_runtime.h>

#define LEVELS 16
#define TSIZE 524288
#define TMASK (TSIZE - 1)
#define TPB 256
#define GPPT 8                  // gather: points per thread
#define CHUNK (TPB * GPPT)      // 2048 points per chunk/slab

typedef float f2v __attribute__((ext_vector_type(2)));
typedef float f4v __attribute__((ext_vector_type(4)));

// int(16 * 1.5**l), exact as float32
__device__ __constant__ float c_res[LEVELS] = {
    16.f, 24.f, 36.f, 54.f, 81.f, 121.f, 182.f, 273.f,
    410.f, 615.f, 922.f, 1383.f, 2075.f, 3113.f, 4670.f, 7006.f
};

__device__ __forceinline__ unsigned hash_idx(float px, float py, float pz, float r)
{
    const int ix = (int)floorf(px * r);
    const int iy = (int)floorf(py * r);
    const int iz = (int)floorf(pz * r);
    const unsigned h = (unsigned)ix * 73856093u
                     ^ (unsigned)iy * 19349663u
                     ^ (unsigned)iz * 83492791u;
    return h & TMASK;
}

// Evidence ledger (rounds 1-5):
//  R1 8-deep gather batching: null -> not per-wave-MLP-limited.
//  R2 spin-flag fusion: 3x regression -> never trade resident miss
//     parallelism for sync.
//  R3 NT x loads: FETCH -150MB but +20us -> x-stream LATENCY is on the
//     critical resource (MSHR slot-cycles), keep hot streams cached.
//  R4 paired-f4v NT stores (16B/lane @ 64B stride): WRITE 262->633MB RMW
//     blowup -> NT store insts must cover full contiguous lines per wave.
//  R5 LDS-staged x (VMEM insts 40->22, occupancy 82->61%): null -> not
//     request-slot- or occupancy-limited. Model: outstanding-line capacity
//     x latency. tables 33.5M@~200cy irreducible; x 6.3M@~550cy removable.
// R6 (this): precompute idx once (24MB read, 128MB write) -> gather's
//     16x cross-level x re-read (384MB, 6.3M L3-latency misses) becomes a
//     128MB idx stream (2.1M misses). Final discriminator vs
//     L2-request-throughput model (null -> 333us config is the roofline).

// idx layout: chunk-tiled like ws: idxw[(c*LEVELS + l)*CHUNK + local]
// (per gather-block 8KB contiguous; no power-of-2 MiB stream spacing)

// ---------------- Kernel 0: per-chunk hash precompute ------------------------
__global__ __launch_bounds__(TPB) void hash_kernel(
    const float* __restrict__ x,
    unsigned* __restrict__ idxw,
    int n)
{
    __shared__ float xs[CHUNK * 3];         // 24KB: this chunk's x
    const int c = blockIdx.x;
    const int t = threadIdx.x;
    const long long base = (long long)c * CHUNK;
    unsigned* __restrict__ islab = idxw + (size_t)c * LEVELS * CHUNK;

    if (base + CHUNK <= n) {
        // stage x: 6 coalesced f4v loads/thread (proven R5 pattern)
        const f4v* __restrict__ xg = reinterpret_cast<const f4v*>(x + 3 * base);
#pragma unroll
        for (int j = 0; j < 6; ++j) {
            const int s = j * TPB + t;
            *reinterpret_cast<f4v*>(&xs[4 * s]) = xg[s];
        }
        __syncthreads();

        // 16 hashes per point; NT stores: per (j,l) wave-inst = 256B
        // contiguous = 4 full lines (islab 128KB-aligned) -> no RMW
#pragma unroll
        for (int j = 0; j < GPPT; ++j) {
            const int local = j * TPB + t;
            const float px = xs[3 * local + 0];
            const float py = xs[3 * local + 1];
            const float pz = xs[3 * local + 2];
#pragma unroll
            for (int l = 0; l < LEVELS; ++l) {
                const unsigned id = hash_idx(px, py, pz, c_res[l]);
                __builtin_nontemporal_store(id, islab + l * CHUNK + local);
            }
        }
    } else {
        // tail: guarded, cached stores (partial lines OK through L2)
        for (int j = 0; j < GPPT; ++j) {
            const int local = j * TPB + t;
            const long long p = base + local;
            if (p < n) {
                const float px = x[3 * p + 0];
                const float py = x[3 * p + 1];
                const float pz = x[3 * p + 2];
                for (int l = 0; l < LEVELS; ++l)
                    islab[l * CHUNK + local] = hash_idx(px, py, pz, c_res[l]);
            }
        }
    }
}

// ---------------- Kernel A: XCD-pinned level-major gather (idx-fed) ----------
// grid = 2 halves x 8 x bpl. Block b: level = half*8 + (b%8) -> XCD b%8
// serves one 4MB table per half from its L2. Reads its chunk's idx slab
// (8KB coalesced, cached) instead of x. Slab stores: interleaved f2v NT
// (512B contiguous/wave-inst = full lines).
__global__ __launch_bounds__(TPB) void gather_kernel(
    const unsigned* __restrict__ idxr,
    const float* __restrict__ tables,
    f2v* __restrict__ ws,
    int n, int bpl)
{
    const int b = blockIdx.x;
    const int half = b / (8 * bpl);
    const int r = b % (8 * bpl);
    const int level = half * 8 + (r & 7);
    const int c = r >> 3;                   // chunk id
    const int t = threadIdx.x;

    const float* __restrict__ tbl = tables + (size_t)level * (TSIZE * 2);
    f2v* __restrict__ slab = ws + ((size_t)c * LEVELS + level) * CHUNK;
    const unsigned* __restrict__ islab = idxr + ((size_t)c * LEVELS + level) * CHUNK;
    const long long base = (long long)c * CHUNK;

    if (base + CHUNK <= n) {
        unsigned idx[GPPT];
#pragma unroll
        for (int j = 0; j < GPPT; ++j)
            idx[j] = islab[j * TPB + t];

        // 8 independent random 8B gathers in flight (XCD-local L2)
        f2v e[GPPT];
#pragma unroll
        for (int j = 0; j < GPPT; ++j)
            e[j] = *reinterpret_cast<const f2v*>(tbl + 2 * (size_t)idx[j]);

#pragma unroll
        for (int j = 0; j < GPPT; ++j)
            __builtin_nontemporal_store(e[j], slab + j * TPB + t);
    } else {
        for (int j = 0; j < GPPT; ++j) {
            const int local = j * TPB + t;
            if (base + local < n) {
                const unsigned id = islab[local];
                const f2v e = *reinterpret_cast<const f2v*>(tbl + 2 * (size_t)id);
                __builtin_nontemporal_store(e, slab + local);
            }
        }
    }
}

// ------------- Kernel A': x-fed gather (fallback when idx doesn't fit) -------
__global__ __launch_bounds__(TPB) void gather_x_kernel(
    const float* __restrict__ x,
    const float* __restrict__ tables,
    f2v* __restrict__ ws,
    int n, int bpl)
{
    const int b = blockIdx.x;
    const int half = b / (8 * bpl);
    const int r = b % (8 * bpl);
    const int level = half * 8 + (r & 7);
    const int c = r >> 3;
    const int t = threadIdx.x;

    const float rs = c_res[level];
    const float* __restrict__ tbl = tables + (size_t)level * (TSIZE * 2);
    f2v* __restrict__ slab = ws + ((size_t)c * LEVELS + level) * CHUNK;
    const long long base = (long long)c * CHUNK;

    if (base + CHUNK <= n) {
        const float* __restrict__ xb = x + 3 * base;
        float px[GPPT], py[GPPT], pz[GPPT];
#pragma unroll
        for (int j = 0; j < GPPT; ++j) {
            const int local = j * TPB + t;
            px[j] = xb[3 * local + 0];
            py[j] = xb[3 * local + 1];
            pz[j] = xb[3 * local + 2];
        }
        unsigned idx[GPPT];
#pragma unroll
        for (int j = 0; j < GPPT; ++j)
            idx[j] = hash_idx(px[j], py[j], pz[j], rs);
        f2v e[GPPT];
#pragma unroll
        for (int j = 0; j < GPPT; ++j)
            e[j] = *reinterpret_cast<const f2v*>(tbl + 2 * (size_t)idx[j]);
#pragma unroll
        for (int j = 0; j < GPPT; ++j)
            __builtin_nontemporal_store(e[j], slab + j * TPB + t);
    } else {
#pragma unroll
        for (int j = 0; j < GPPT; ++j) {
            const int local = j * TPB + t;
            const long long p = base + local;
            if (p < n) {
                const float qx = x[3 * p + 0];
                const float qy = x[3 * p + 1];
                const float qz = x[3 * p + 2];
                const unsigned idx = hash_idx(qx, qy, qz, rs);
                const f2v e = *reinterpret_cast<const f2v*>(tbl + 2 * (size_t)idx);
                __builtin_nontemporal_store(e, slab + local);
            }
        }
    }
}

// ---------------- Kernel B: assemble (slab ws -> point-major out rows) -------
// At HBM roofline for its 524MB (~6TB/s measured). Unchanged.
__global__ __launch_bounds__(TPB) void assemble_kernel(
    const f2v* __restrict__ ws,
    float* __restrict__ out,
    int n)
{
    const int c = blockIdx.x;
    const int t = threadIdx.x;
    const int q = t & 7;
    const int sub = t >> 3;  // 0..31

    const f2v* __restrict__ wa = ws + ((size_t)c * LEVELS + 2 * q) * CHUNK;
    const f2v* __restrict__ wb = wa + CHUNK;
    const long long base = (long long)c * CHUNK;

    if (base + CHUNK <= n) {
#pragma unroll 8
        for (int u = 0; u < CHUNK / 64; ++u) {
            const int lp = 2 * (u * 32 + sub);
            const f4v a = __builtin_nontemporal_load(
                reinterpret_cast<const f4v*>(wa + lp));
            const f4v b = __builtin_nontemporal_load(
                reinterpret_cast<const f4v*>(wb + lp));
            f4v v0, v1;
            v0.x = a.x; v0.y = a.y; v0.z = b.x; v0.w = b.y;
            v1.x = a.z; v1.y = a.w; v1.z = b.z; v1.w = b.w;
            float* row = out + (size_t)(base + lp) * (2 * LEVELS) + 4 * q;
            __builtin_nontemporal_store(v0, reinterpret_cast<f4v*>(row));
            __builtin_nontemporal_store(v1, reinterpret_cast<f4v*>(row + 2 * LEVELS));
        }
    } else {
#pragma unroll 8
        for (int u = 0; u < CHUNK / 32; ++u) {
            const int lp = u * 32 + sub;
            const long long pt = base + lp;
            if (pt < n) {
                const f2v a = __builtin_nontemporal_load(wa + lp);
                const f2v b = __builtin_nontemporal_load(wb + lp);
                f4v v;
                v.x = a.x; v.y = a.y; v.z = b.x; v.w = b.y;
                __builtin_nontemporal_store(
                    v, reinterpret_cast<f4v*>(out + (size_t)pt * (2 * LEVELS) + 4 * q));
            }
        }
    }
}

// ---------------- Fallback (ws too small): round-3 fused kernel --------------
#define ROWW 34
__global__ __launch_bounds__(TPB) void hashgrid_fused(
    const float* __restrict__ x,
    const float* __restrict__ tables,
    float* __restrict__ out,
    int n)
{
    __shared__ float lds[TPB * ROWW];
    const int t = threadIdx.x;

    for (long long base = (long long)blockIdx.x * TPB; base < n;
         base += (long long)gridDim.x * TPB) {
        const int p = (int)base + t;
        float px = 0.f, py = 0.f, pz = 0.f;
        if (p < n) {
            px = x[3 * (size_t)p + 0];
            py = x[3 * (size_t)p + 1];
            pz = x[3 * (size_t)p + 2];
        }
#pragma unroll
        for (int l = 0; l < LEVELS; ++l) {
            if (p < n) {
                const unsigned idx = hash_idx(px, py, pz, c_res[l]);
                const f2v e = *reinterpret_cast<const f2v*>(
                    tables + (((size_t)l * TSIZE + idx) << 1));
                *reinterpret_cast<f2v*>(lds + t * ROWW + 2 * l) = e;
            }
            __syncthreads();
        }
#pragma unroll
        for (int it = 0; it < 8; ++it) {
            const int lp = it * 32 + (t >> 3);
            const int qq = t & 7;
            const int gp = (int)base + lp;
            if (gp < n) {
                const f2v a = *reinterpret_cast<const f2v*>(lds + lp * ROWW + 4 * qq);
                const f2v b = *reinterpret_cast<const f2v*>(lds + lp * ROWW + 4 * qq + 2);
                f4v v;
                v.x = a.x; v.y = a.y; v.z = b.x; v.w = b.y;
                __builtin_nontemporal_store(
                    v, reinterpret_cast<f4v*>(out + (size_t)gp * (2 * LEVELS) + 4 * qq));
            }
        }
        __syncthreads();
    }
}

extern "C" void kernel_launch(void* const* d_in, const int* in_sizes, int n_in,
                              void* d_out, int out_size, void* d_ws, size_t ws_size,
                              hipStream_t stream)
{
    const float* x      = (const float*)d_in[0];   // [N, 3]
    const float* tables = (const float*)d_in[1];   // [L, T, F]
    float* out          = (float*)d_out;           // [N, L*F]
    const int n = in_sizes[0] / 3;

    const int bpl = (n + CHUNK - 1) / CHUNK;       // chunks (= blocks per level)
    const size_t slab_bytes = (size_t)bpl * LEVELS * CHUNK * sizeof(f2v);
    const size_t idx_bytes  = (size_t)bpl * LEVELS * CHUNK * sizeof(unsigned);

    if (ws_size < slab_bytes) {
        // can't even hold slabs: round-3 fused kernel
        int grid = 1024;
        const int nblocks = (n + TPB - 1) / TPB;
        if (nblocks < grid) grid = nblocks;
        hashgrid_fused<<<grid, TPB, 0, stream>>>(x, tables, out, n);
        return;
    }

    f2v* ws = (f2v*)d_ws;

    if (ws_size >= slab_bytes + idx_bytes) {
        // full path: precompute idx, idx-fed gather, assemble
        unsigned* idxw = (unsigned*)((char*)d_ws + slab_bytes);
        hash_kernel<<<bpl, TPB, 0, stream>>>(x, idxw, n);
        gather_kernel<<<2 * 8 * bpl, TPB, 0, stream>>>(idxw, tables, ws, n, bpl);
    } else {
        // proven 333us path
        gather_x_kernel<<<2 * 8 * bpl, TPB, 0, stream>>>(x, tables, ws, n, bpl);
    }
    assemble_kernel<<<bpl, TPB, 0, stream>>>(ws, out, n);
}

// Round 7
// 321.467 us; speedup vs baseline: 1.0933x; 1.0933x over previous
//
#include <hip/hip_runtime.h>

#define LEVELS 16
#define TSIZE 524288
#define TMASK (TSIZE - 1)
#define TPB 256
#define GPPT 8                  // gather: points per thread
#define CHUNK (TPB * GPPT)      // 2048 points per chunk/slab

typedef float f2v __attribute__((ext_vector_type(2)));
typedef float f4v __attribute__((ext_vector_type(4)));

// int(16 * 1.5**l), exact as float32
__device__ __constant__ float c_res[LEVELS] = {
    16.f, 24.f, 36.f, 54.f, 81.f, 121.f, 182.f, 273.f,
    410.f, 615.f, 922.f, 1383.f, 2075.f, 3113.f, 4670.f, 7006.f
};

__device__ __forceinline__ unsigned hash_idx(float px, float py, float pz, float r)
{
    const int ix = (int)floorf(px * r);
    const int iy = (int)floorf(py * r);
    const int iz = (int)floorf(pz * r);
    const unsigned h = (unsigned)ix * 73856093u
                     ^ (unsigned)iy * 19349663u
                     ^ (unsigned)iz * 83492791u;
    return h & TMASK;
}

// Evidence ledger (rounds 1-6):
//  R1 8-deep gather batching: null -> not per-wave-MLP-limited.
//  R2 spin-flag fusion: 3x regression -> never trade resident miss
//     parallelism for sync.
//  R3 NT x loads: FETCH -150MB but +20us -> feeder-stream LATENCY is on
//     the critical resource (slot-cycles = misses x latency).
//  R4 paired-f4v NT stores (16B/lane @ 64B stride): WRITE 262->633MB RMW
//     blowup -> NT store insts must cover full contiguous lines per wave.
//  R5 LDS-staged x (VMEM insts 40->22, occ 82->61%): null -> not
//     request-slot- or occupancy-limited.
//  R6 idx-precompute with NT idx stores: FETCH -240MB but gather +35us.
//     NT pushed idx to HBM -> consumer pays 900cy instead of x's ~600cy;
//     slot-cycle product got WORSE. Feeder must be cache-resident.
//  R7 (this): identical to R6 except idx stores are CACHED -> writebacks
//     land in the 256MB memory-side L3; gather's idx reads become L3 hits
//     (~550cy, 2.1M misses = 1.2G slot-cycles vs x-fed 3.5G).
//     Model (B) latency-capacity -> gather ~205us, total ~320.
//     Null -> L2-request-throughput floor; revert to 333us config = roofline.

// idx layout: chunk-tiled like ws: idxw[(c*LEVELS + l)*CHUNK + local]

// ---------------- Kernel 0: per-chunk hash precompute ------------------------
__global__ __launch_bounds__(TPB) void hash_kernel(
    const float* __restrict__ x,
    unsigned* __restrict__ idxw,
    int n)
{
    __shared__ float xs[CHUNK * 3];         // 24KB: this chunk's x
    const int c = blockIdx.x;
    const int t = threadIdx.x;
    const long long base = (long long)c * CHUNK;
    unsigned* __restrict__ islab = idxw + (size_t)c * LEVELS * CHUNK;

    if (base + CHUNK <= n) {
        // stage x: 6 coalesced f4v loads/thread (proven R5 pattern)
        const f4v* __restrict__ xg = reinterpret_cast<const f4v*>(x + 3 * base);
#pragma unroll
        for (int j = 0; j < 6; ++j) {
            const int s = j * TPB + t;
            *reinterpret_cast<f4v*>(&xs[4 * s]) = xg[s];
        }
        __syncthreads();

        // 16 hashes per point; CACHED stores (R7: must land in L3, not HBM).
        // Per (j,l) wave-inst: 256B contiguous -> full lines, clean writeback.
#pragma unroll
        for (int j = 0; j < GPPT; ++j) {
            const int local = j * TPB + t;
            const float px = xs[3 * local + 0];
            const float py = xs[3 * local + 1];
            const float pz = xs[3 * local + 2];
#pragma unroll
            for (int l = 0; l < LEVELS; ++l)
                islab[l * CHUNK + local] = hash_idx(px, py, pz, c_res[l]);
        }
    } else {
        // tail: guarded, cached stores
        for (int j = 0; j < GPPT; ++j) {
            const int local = j * TPB + t;
            const long long p = base + local;
            if (p < n) {
                const float px = x[3 * p + 0];
                const float py = x[3 * p + 1];
                const float pz = x[3 * p + 2];
                for (int l = 0; l < LEVELS; ++l)
                    islab[l * CHUNK + local] = hash_idx(px, py, pz, c_res[l]);
            }
        }
    }
}

// ---------------- Kernel A: XCD-pinned level-major gather (idx-fed) ----------
// grid = 2 halves x 8 x bpl. Block b: level = half*8 + (b%8) -> XCD b%8
// serves one 4MB table per half from its L2. Reads its chunk's idx slab
// (8KB coalesced, L3-resident). Slab stores: interleaved f2v NT
// (512B contiguous/wave-inst = full lines).
__global__ __launch_bounds__(TPB) void gather_kernel(
    const unsigned* __restrict__ idxr,
    const float* __restrict__ tables,
    f2v* __restrict__ ws,
    int n, int bpl)
{
    const int b = blockIdx.x;
    const int half = b / (8 * bpl);
    const int r = b % (8 * bpl);
    const int level = half * 8 + (r & 7);
    const int c = r >> 3;                   // chunk id
    const int t = threadIdx.x;

    const float* __restrict__ tbl = tables + (size_t)level * (TSIZE * 2);
    f2v* __restrict__ slab = ws + ((size_t)c * LEVELS + level) * CHUNK;
    const unsigned* __restrict__ islab = idxr + ((size_t)c * LEVELS + level) * CHUNK;
    const long long base = (long long)c * CHUNK;

    if (base + CHUNK <= n) {
        unsigned idx[GPPT];
#pragma unroll
        for (int j = 0; j < GPPT; ++j)
            idx[j] = islab[j * TPB + t];

        // 8 independent random 8B gathers in flight (XCD-local L2)
        f2v e[GPPT];
#pragma unroll
        for (int j = 0; j < GPPT; ++j)
            e[j] = *reinterpret_cast<const f2v*>(tbl + 2 * (size_t)idx[j]);

#pragma unroll
        for (int j = 0; j < GPPT; ++j)
            __builtin_nontemporal_store(e[j], slab + j * TPB + t);
    } else {
        for (int j = 0; j < GPPT; ++j) {
            const int local = j * TPB + t;
            if (base + local < n) {
                const unsigned id = islab[local];
                const f2v e = *reinterpret_cast<const f2v*>(tbl + 2 * (size_t)id);
                __builtin_nontemporal_store(e, slab + local);
            }
        }
    }
}

// ------------- Kernel A': x-fed gather (fallback when idx doesn't fit) -------
__global__ __launch_bounds__(TPB) void gather_x_kernel(
    const float* __restrict__ x,
    const float* __restrict__ tables,
    f2v* __restrict__ ws,
    int n, int bpl)
{
    const int b = blockIdx.x;
    const int half = b / (8 * bpl);
    const int r = b % (8 * bpl);
    const int level = half * 8 + (r & 7);
    const int c = r >> 3;
    const int t = threadIdx.x;

    const float rs = c_res[level];
    const float* __restrict__ tbl = tables + (size_t)level * (TSIZE * 2);
    f2v* __restrict__ slab = ws + ((size_t)c * LEVELS + level) * CHUNK;
    const long long base = (long long)c * CHUNK;

    if (base + CHUNK <= n) {
        const float* __restrict__ xb = x + 3 * base;
        float px[GPPT], py[GPPT], pz[GPPT];
#pragma unroll
        for (int j = 0; j < GPPT; ++j) {
            const int local = j * TPB + t;
            px[j] = xb[3 * local + 0];
            py[j] = xb[3 * local + 1];
            pz[j] = xb[3 * local + 2];
        }
        unsigned idx[GPPT];
#pragma unroll
        for (int j = 0; j < GPPT; ++j)
            idx[j] = hash_idx(px[j], py[j], pz[j], rs);
        f2v e[GPPT];
#pragma unroll
        for (int j = 0; j < GPPT; ++j)
            e[j] = *reinterpret_cast<const f2v*>(tbl + 2 * (size_t)idx[j]);
#pragma unroll
        for (int j = 0; j < GPPT; ++j)
            __builtin_nontemporal_store(e[j], slab + j * TPB + t);
    } else {
#pragma unroll
        for (int j = 0; j < GPPT; ++j) {
            const int local = j * TPB + t;
            const long long p = base + local;
            if (p < n) {
                const float qx = x[3 * p + 0];
                const float qy = x[3 * p + 1];
                const float qz = x[3 * p + 2];
                const unsigned idx = hash_idx(qx, qy, qz, rs);
                const f2v e = *reinterpret_cast<const f2v*>(tbl + 2 * (size_t)idx);
                __builtin_nontemporal_store(e, slab + local);
            }
        }
    }
}

// ---------------- Kernel B: assemble (slab ws -> point-major out rows) -------
// At HBM roofline for its 524MB (~6TB/s measured). Unchanged.
__global__ __launch_bounds__(TPB) void assemble_kernel(
    const f2v* __restrict__ ws,
    float* __restrict__ out,
    int n)
{
    const int c = blockIdx.x;
    const int t = threadIdx.x;
    const int q = t & 7;
    const int sub = t >> 3;  // 0..31

    const f2v* __restrict__ wa = ws + ((size_t)c * LEVELS + 2 * q) * CHUNK;
    const f2v* __restrict__ wb = wa + CHUNK;
    const long long base = (long long)c * CHUNK;

    if (base + CHUNK <= n) {
#pragma unroll 8
        for (int u = 0; u < CHUNK / 64; ++u) {
            const int lp = 2 * (u * 32 + sub);
            const f4v a = __builtin_nontemporal_load(
                reinterpret_cast<const f4v*>(wa + lp));
            const f4v b = __builtin_nontemporal_load(
                reinterpret_cast<const f4v*>(wb + lp));
            f4v v0, v1;
            v0.x = a.x; v0.y = a.y; v0.z = b.x; v0.w = b.y;
            v1.x = a.z; v1.y = a.w; v1.z = b.z; v1.w = b.w;
            float* row = out + (size_t)(base + lp) * (2 * LEVELS) + 4 * q;
            __builtin_nontemporal_store(v0, reinterpret_cast<f4v*>(row));
            __builtin_nontemporal_store(v1, reinterpret_cast<f4v*>(row + 2 * LEVELS));
        }
    } else {
#pragma unroll 8
        for (int u = 0; u < CHUNK / 32; ++u) {
            const int lp = u * 32 + sub;
            const long long pt = base + lp;
            if (pt < n) {
                const f2v a = __builtin_nontemporal_load(wa + lp);
                const f2v b = __builtin_nontemporal_load(wb + lp);
                f4v v;
                v.x = a.x; v.y = a.y; v.z = b.x; v.w = b.y;
                __builtin_nontemporal_store(
                    v, reinterpret_cast<f4v*>(out + (size_t)pt * (2 * LEVELS) + 4 * q));
            }
        }
    }
}

// ---------------- Fallback (ws too small): round-3 fused kernel --------------
#define ROWW 34
__global__ __launch_bounds__(TPB) void hashgrid_fused(
    const float* __restrict__ x,
    const float* __restrict__ tables,
    float* __restrict__ out,
    int n)
{
    __shared__ float lds[TPB * ROWW];
    const int t = threadIdx.x;

    for (long long base = (long long)blockIdx.x * TPB; base < n;
         base += (long long)gridDim.x * TPB) {
        const int p = (int)base + t;
        float px = 0.f, py = 0.f, pz = 0.f;
        if (p < n) {
            px = x[3 * (size_t)p + 0];
            py = x[3 * (size_t)p + 1];
            pz = x[3 * (size_t)p + 2];
        }
#pragma unroll
        for (int l = 0; l < LEVELS; ++l) {
            if (p < n) {
                const unsigned idx = hash_idx(px, py, pz, c_res[l]);
                const f2v e = *reinterpret_cast<const f2v*>(
                    tables + (((size_t)l * TSIZE + idx) << 1));
                *reinterpret_cast<f2v*>(lds + t * ROWW + 2 * l) = e;
            }
            __syncthreads();
        }
#pragma unroll
        for (int it = 0; it < 8; ++it) {
            const int lp = it * 32 + (t >> 3);
            const int qq = t & 7;
            const int gp = (int)base + lp;
            if (gp < n) {
                const f2v a = *reinterpret_cast<const f2v*>(lds + lp * ROWW + 4 * qq);
                const f2v b = *reinterpret_cast<const f2v*>(lds + lp * ROWW + 4 * qq + 2);
                f4v v;
                v.x = a.x; v.y = a.y; v.z = b.x; v.w = b.y;
                __builtin_nontemporal_store(
                    v, reinterpret_cast<f4v*>(out + (size_t)gp * (2 * LEVELS) + 4 * qq));
            }
        }
        __syncthreads();
    }
}

extern "C" void kernel_launch(void* const* d_in, const int* in_sizes, int n_in,
                              void* d_out, int out_size, void* d_ws, size_t ws_size,
                              hipStream_t stream)
{
    const float* x      = (const float*)d_in[0];   // [N, 3]
    const float* tables = (const float*)d_in[1];   // [L, T, F]
    float* out          = (float*)d_out;           // [N, L*F]
    const int n = in_sizes[0] / 3;

    const int bpl = (n + CHUNK - 1) / CHUNK;       // chunks (= blocks per level)
    const size_t slab_bytes = (size_t)bpl * LEVELS * CHUNK * sizeof(f2v);
    const size_t idx_bytes  = (size_t)bpl * LEVELS * CHUNK * sizeof(unsigned);

    if (ws_size < slab_bytes) {
        // can't even hold slabs: round-3 fused kernel
        int grid = 1024;
        const int nblocks = (n + TPB - 1) / TPB;
        if (nblocks < grid) grid = nblocks;
        hashgrid_fused<<<grid, TPB, 0, stream>>>(x, tables, out, n);
        return;
    }

    f2v* ws = (f2v*)d_ws;

    if (ws_size >= slab_bytes + idx_bytes) {
        // full path: precompute idx (cached -> L3), idx-fed gather, assemble
        unsigned* idxw = (unsigned*)((char*)d_ws + slab_bytes);
        hash_kernel<<<bpl, TPB, 0, stream>>>(x, idxw, n);
        gather_kernel<<<2 * 8 * bpl, TPB, 0, stream>>>(idxw, tables, ws, n, bpl);
    } else {
        // proven 333us path
        gather_x_kernel<<<2 * 8 * bpl, TPB, 0, stream>>>(x, tables, ws, n, bpl);
    }
    assemble_kernel<<<bpl, TPB, 0, stream>>>(ws, out, n);
}